// Round 4
// baseline (133.209 us; speedup 1.0000x reference)
//
#include <hip/hip_runtime.h>
#include <stdint.h>

typedef unsigned int u32;
typedef unsigned long long u64;
typedef unsigned char u8;

#define OCC_THR   0.5f
#define RADIUS_F  1.0f
#define MAXP      8192
#define K1_TT     128     // true points per y-block in k_build
#define K2_THREADS 512
#define PER       8       // true points per thread in k_match (4096/512)
#define POOLCAP   24      // per-thread LDS candidate pool slots

// ---------------- Kernel 1: build candidate lists, zero-init-free ----------
// Block (bx,by): preds [bx*256,+256) x trues [by*128,+128). Partition p = bx.
// Per-block counts live in LDS; final per-(true,partition) count byte is
// written UNCONDITIONALLY -> no global pre-zeroing needed (poison-safe).
__global__ void __launch_bounds__(256) k_build(
    const float4* __restrict__ pred, const float4* __restrict__ tru,
    int n_pred, int n_true, int npart, int partcap,
    u8* __restrict__ counts8, u64* __restrict__ cands)
{
    __shared__ float4 st[K1_TT];
    __shared__ u32    lcnt[K1_TT];
    const int tid = threadIdx.x;
    const int p   = blockIdx.x;                 // partition index
    const int j   = p * 256 + tid;              // pred index
    const int ti0 = blockIdx.y * K1_TT;

    for (int t = tid; t < K1_TT; t += 256) {
        int i = ti0 + t;
        st[t]   = (i < n_true) ? tru[i] : make_float4(1e30f, 1e30f, 1e30f, 0.0f);
        lcnt[t] = 0;
    }
    __syncthreads();

    const int tmax = min(K1_TT, n_true - ti0);
    if (j < n_pred) {
        const float4 pt = pred[j];
        if (pt.w >= OCC_THR) {
            for (int t = 0; t < tmax; ++t) {
                float4 q = st[t];
                float dx = q.x - pt.x, dy = q.y - pt.y, dz = q.z - pt.z;
                float d2 = dx*dx + dy*dy + dz*dz;
                float d  = sqrtf(d2);
                if (d <= RADIUS_F) {
                    int i = ti0 + t;
                    u32 slot = atomicAdd(&lcnt[t], 1u);
                    if ((int)slot < partcap) {
                        u64 key = ((u64)__float_as_uint(d) << 32) | (u32)j;
                        cands[((size_t)i * npart + p) * partcap + slot] = key;
                    }
                }
            }
        }
    }
    __syncthreads();

    for (int t = tid; t < tmax; t += 256) {
        u32 c = lcnt[t];
        if (c > (u32)partcap) c = (u32)partcap;
        counts8[(size_t)(ti0 + t) * npart + p] = (u8)c;
    }
}

// ---------------- Kernel 2: parallel exact greedy via deferred acceptance ----
// Sequential greedy (serial dictatorship by true index) == unique stable
// matching under a common pred-side preference order (the tag). Computed
// order-independently by Gale-Shapley: owner[j] = min tag that proposed to j.
__global__ void __launch_bounds__(K2_THREADS) k_match(
    const float4* __restrict__ pred, const float4* __restrict__ tru,
    int n_pred, int n_true, int npart, int partcap,
    const u8* __restrict__ counts8,
    const u64* __restrict__ cands,
    float* __restrict__ out)
{
    __shared__ u32   s_owner[MAXP];                 // 32 KB
    __shared__ u64   s_pool[K2_THREADS * POOLCAP];  // 96 KB
    __shared__ int   s_flag;
    __shared__ int   s_numtrue;
    __shared__ float s_rd[8], s_rq[8];
    __shared__ int   s_rc[8];

    const int tid = threadIdx.x;
    if (tid == 0) s_numtrue = 0;
    for (int j = tid; j < MAXP; j += K2_THREADS) s_owner[j] = 0xFFFFFFFFu;

    // ---- prologue: load counts, compact candidates into per-thread pool ----
    u32  eff[PER];  float tp[PER];  u32 curj[PER];  float dist[PER];
    u32  off[PER];                       // pool offset, 0xFFFFFFFF => global path
    bool searching[PER];
    int myvalid = 0;
    u32 used = 0;
    const u32 poolbase = (u32)tid * POOLCAP;

#pragma unroll
    for (int k = 0; k < PER; ++k) {
        const int i = tid * PER + k;
        eff[k] = 0; tp[k] = 0.0f; curj[k] = 0xFFFFFFFFu; dist[k] = 0.0f;
        off[k] = 0xFFFFFFFFu; searching[k] = false;
        if (i < n_true) {
            float4 q = tru[i];
            tp[k] = q.w;
            if (q.w >= OCC_THR) {
                myvalid++;
                const u8* crow = counts8 + (size_t)i * npart;
                u32 cw[8];
                if (npart == 32) {
                    const uint4* cv = (const uint4*)crow;
                    uint4 a = cv[0], b = cv[1];
                    cw[0]=a.x; cw[1]=a.y; cw[2]=a.z; cw[3]=a.w;
                    cw[4]=b.x; cw[5]=b.y; cw[6]=b.z; cw[7]=b.w;
                } else {
                    for (int w = 0; w < 8; ++w) cw[w] = 0;
                    for (int p = 0; p < npart; ++p)
                        cw[p >> 2] |= ((u32)crow[p]) << ((p & 3) * 8);
                }
                u32 e = 0;
                for (int w = 0; w < 8; ++w) {
                    u32 v = cw[w];
                    e += (v & 0xFFu) + ((v >> 8) & 0xFFu) + ((v >> 16) & 0xFFu) + (v >> 24);
                }
                eff[k] = e;
                if (e > 0u) {
                    searching[k] = true;
                    if (used + e <= POOLCAP) {
                        off[k] = poolbase + used;
                        u32 w = off[k];
                        const u64* row = cands + (size_t)i * npart * partcap;
                        for (int p = 0; p < npart; ++p) {
                            u32 c = (cw[p >> 2] >> ((p & 3) * 8)) & 0xFFu;
                            for (u32 s = 0; s < c; ++s)
                                s_pool[w++] = row[(size_t)p * partcap + s];
                        }
                        used += e;
                    } // else: off stays sentinel -> exact global rescan path
                }
            }
        }
    }
    if (myvalid) atomicAdd(&s_numtrue, myvalid);
    __syncthreads();

    // ---- deferred-acceptance rounds ----
    for (;;) {
        if (tid == 0) s_flag = 0;
        __syncthreads();

        u64 prop[PER];
#pragma unroll
        for (int k = 0; k < PER; ++k) {
            prop[k] = ~0ull;
            if (searching[k]) {
                const u32 i = (u32)(tid * PER + k);
                u64 best = ~0ull;
                if (off[k] != 0xFFFFFFFFu) {
                    const u32 b = off[k];
                    for (u32 kk = 0; kk < eff[k]; ++kk) {
                        u64 c = s_pool[b + kk];
                        if (s_owner[(u32)c] > i && c < best) best = c;
                    }
                } else {
                    const u8*  crow = counts8 + (size_t)i * npart;
                    const u64* row  = cands + (size_t)i * npart * partcap;
                    for (int p = 0; p < npart; ++p) {
                        u32 c = crow[p];
                        for (u32 s = 0; s < c; ++s) {
                            u64 cd = row[(size_t)p * partcap + s];
                            if (s_owner[(u32)cd] > i && cd < best) best = cd;
                        }
                    }
                }
                if (best != ~0ull) {
                    atomicMin(&s_owner[(u32)best], i);
                    prop[k] = best;
                } else {
                    searching[k] = false;   // exhausted -> final unmatched
                }
            }
        }
        __syncthreads();

        bool any = false;
#pragma unroll
        for (int k = 0; k < PER; ++k) {
            const u32 i = (u32)(tid * PER + k);
            if (prop[k] != ~0ull) {
                const u32 j = (u32)prop[k];
                if (s_owner[j] == i) {            // tentative hold
                    curj[k] = j;
                    dist[k] = __uint_as_float((u32)(prop[k] >> 32));
                    searching[k] = false;
                } else {
                    any = true;                    // rejected -> retry
                }
            } else if (curj[k] != 0xFFFFFFFFu) {
                if (s_owner[curj[k]] != i) {       // evicted by lower tag
                    curj[k] = 0xFFFFFFFFu;
                    searching[k] = true;
                    any = true;
                }
            }
        }
        if (any) s_flag = 1;
        __syncthreads();
        if (!s_flag) break;
    }

    // ---- accumulate ----
    float sd = 0.0f, sq = 0.0f; int cnt = 0;
#pragma unroll
    for (int k = 0; k < PER; ++k) {
        if (curj[k] != 0xFFFFFFFFu) {
            sd += dist[k];
            float pw = pred[curj[k]].w;            // scattered, L2-hot
            float df = tp[k] - pw;
            sq += df * df;
            cnt++;
        }
    }
    for (int o = 32; o > 0; o >>= 1) {
        sd  += __shfl_down(sd,  o, 64);
        sq  += __shfl_down(sq,  o, 64);
        cnt += __shfl_down(cnt, o, 64);
    }
    const int wave = tid >> 6;
    if ((tid & 63) == 0) { s_rd[wave] = sd; s_rq[wave] = sq; s_rc[wave] = cnt; }
    __syncthreads();

    if (tid == 0) {
        float tsd = 0.0f, tsq = 0.0f; int tc = 0;
        for (int w = 0; w < K2_THREADS / 64; ++w) { tsd += s_rd[w]; tsq += s_rq[w]; tc += s_rc[w]; }
        float num_true  = (float)s_numtrue;
        float cnt_f     = (float)tc;
        float unmatched = num_true - cnt_f;
        float denom     = fmaxf(cnt_f, 1.0f);
        bool  has       = tc > 0;
        float spatial   = RADIUS_F * 10.0f * unmatched + (has ? tsd / denom : 0.0f);
        float prob      = unmatched + (has ? tsq / denom : 0.0f);
        out[0] = spatial + prob;
    }
}

// ---------------- launch ----------------
extern "C" void kernel_launch(void* const* d_in, const int* in_sizes, int n_in,
                              void* d_out, int out_size, void* d_ws, size_t ws_size,
                              hipStream_t stream) {
    const float4* pred = (const float4*)d_in[0];
    const float4* tru  = (const float4*)d_in[1];
    const int n_pred = in_sizes[0] / 4;
    const int n_true = in_sizes[1] / 4;

    const int npart = (n_pred + 255) / 256;

    // layout: counts8 [n_true*npart] bytes | cands [n_true*npart*partcap] u64
    size_t counts_bytes = (size_t)n_true * npart;
    size_t cand_off = (counts_bytes + 255) & ~(size_t)255;

    int partcap = 6;
    {
        size_t need = cand_off + (size_t)n_true * npart * partcap * 8;
        if (need > ws_size) {
            size_t avail = (ws_size > cand_off) ? (ws_size - cand_off) : 0;
            long c = (long)(avail / ((size_t)n_true * npart * 8));
            partcap = (int)(c < 1 ? 1 : (c > 6 ? 6 : c));
        }
    }

    u8*  counts8 = (u8*)d_ws;
    u64* cands   = (u64*)((char*)d_ws + cand_off);

    dim3 g1(npart, (n_true + K1_TT - 1) / K1_TT);
    k_build<<<g1, 256, 0, stream>>>(pred, tru, n_pred, n_true, npart, partcap,
                                    counts8, cands);
    k_match<<<1, K2_THREADS, 0, stream>>>(pred, tru, n_pred, n_true, npart, partcap,
                                          counts8, cands, (float*)d_out);
}